// Round 10
// baseline (3174.711 us; speedup 1.0000x reference)
//
#include <hip/hip_runtime.h>

#define T_SEQ 2048
#define NBATCH 64
#define DIM 128      // SEQ_LEN
#define HID 128      // HIDDEN
#define G4 512       // 4*HID
#define LOG2E 1.44269504088896f

typedef _Float16 h2v   __attribute__((ext_vector_type(2)));
typedef _Float16 f16x8 __attribute__((ext_vector_type(8)));
typedef float    f32x4 __attribute__((ext_vector_type(4)));
typedef float    f32x2 __attribute__((ext_vector_type(2)));

__device__ __forceinline__ float rcp_(float x)  { return __builtin_amdgcn_rcpf(x); }
__device__ __forceinline__ float exp2_(float x) { return __builtin_amdgcn_exp2f(x); }
// sigmoid with input pre-scaled by log2e
__device__ __forceinline__ float sig2_(float a) { return rcp_(1.0f + exp2_(-a)); }
// tanh with input pre-scaled by 2*log2e: tanh(x) = 1 - 2/(1+2^a)
__device__ __forceinline__ float tanh2_(float a) {
    return fmaf(-2.0f, rcp_(1.0f + exp2_(a)), 1.0f);
}
// barrier draining ONLY lgkm (ds) — vm loads keep flowing across it
__device__ __forceinline__ void barrier_lgkm() {
    asm volatile("s_waitcnt lgkmcnt(0)\n\ts_barrier" ::: "memory");
    __builtin_amdgcn_sched_barrier(0);
}

// ---- prep: x f32 -> f16 (same layout); pack fcw into pairs; scaled bias ----
__global__ __launch_bounds__(256) void prep(
    const float* __restrict__ x,      // [B][T][DIM] f32
    const float* __restrict__ fcw,    // [2][T*HID]
    const float* __restrict__ bias,   // [G4] gate-major
    _Float16* __restrict__ x16,       // [B][T][DIM] f16
    float* __restrict__ fc2,          // [T*HID][2]
    float* __restrict__ bias_s)       // [512] channel = 4*unit+gate, scaled
{
    const size_t gtid   = (size_t)blockIdx.x * blockDim.x + threadIdx.x;
    const size_t stride = (size_t)gridDim.x * blockDim.x;

    const size_t n_x2 = (size_t)NBATCH * T_SEQ * DIM / 2;
    for (size_t i = gtid; i < n_x2; i += stride) {
        float2 v = reinterpret_cast<const float2*>(x)[i];
        h2v p; p.x = (_Float16)v.x; p.y = (_Float16)v.y;
        reinterpret_cast<h2v*>(x16)[i] = p;
    }
    const size_t n_f = (size_t)T_SEQ * HID;
    for (size_t i = gtid; i < n_f; i += stride) {
        fc2[2 * i]     = fcw[i];
        fc2[2 * i + 1] = fcw[n_f + i];
    }
    for (size_t i = gtid; i < 512; i += stride) {
        int gate = (int)i & 3, u = (int)i >> 2;
        float sc = (gate == 2) ? 2.0f * LOG2E : LOG2E;
        bias_s[i] = bias[gate * HID + u] * sc;
    }
}

// ---- fused scan: 4 blocks x 512 threads, 16 batches/block (R8 mapping).
// Software-pipelined: accX[j] = bias + Wih~.x_{t+1} computed during step t
// (independent 4-chains, fills MFMA gaps); recurrent path is a 4-deep chain
// gates = mfma(aH, h_t, accX). One lgkm-only barrier per step.
// Lane (col=l&15, hi=l>>4), wave w, tile j -> (batch bg*16+col, unit 16w+4j+hi),
// gate regs 0..3 = i,f,g,o (C-layout verified R7/R8).
__global__ __launch_bounds__(512, 1) void lstm_fused(
    const _Float16* __restrict__ x16, // [B][T][DIM] f16
    const float* __restrict__ Wih,    // [DIM][G4]
    const float* __restrict__ Whh,    // [HID][G4]
    const float* __restrict__ h0,
    const float* __restrict__ c0,
    const float* __restrict__ fc2,    // [T*HID][2]
    const float* __restrict__ fcb,
    const float* __restrict__ bias_s, // [512] scaled
    float* __restrict__ out)          // [B][2]
{
    __shared__ _Float16 frag[2][4][64][8];   // 8 KB, double-buffered h B-fragments
    __shared__ float red[8][16][2];

    const int tid = threadIdx.x;
    const int w   = tid >> 6;
    const int l   = tid & 63;
    const int col = l & 15;
    const int hi  = l >> 4;
    const int bg  = blockIdx.x;
    const int batch = bg * 16 + col;

    // ---- static A fragments for both GEMMs (128 VGPR), log2e-scaled f16
    f16x8 aX[4][4], aH[4][4];
    #pragma unroll
    for (int j = 0; j < 4; ++j) {
        const int chr  = 16 * (4 * w + j) + col;          // A-row channel
        const int wcol = (chr & 3) * HID + (chr >> 2);    // weight column
        const float sc = ((chr & 3) == 2) ? 2.0f * LOG2E : LOG2E;
        #pragma unroll
        for (int ks = 0; ks < 4; ++ks) {
            f16x8 ax, ah;
            #pragma unroll
            for (int i = 0; i < 8; ++i) {
                int k = ks * 32 + hi * 8 + i;
                ax[i] = (_Float16)(Wih[(size_t)k * G4 + wcol] * sc);
                ah[i] = (_Float16)(Whh[(size_t)k * G4 + wcol] * sc);
            }
            aX[j][ks] = ax; aH[j][ks] = ah;
        }
    }
    // scaled bias accumulator init (channels 16*(4w+j)+4hi+0..3 consecutive)
    f32x4 bv[4];
    #pragma unroll
    for (int j = 0; j < 4; ++j)
        bv[j] = *reinterpret_cast<const f32x4*>(bias_s + 16 * (4 * w + j) + 4 * hi);

    // state: this lane's 4 units (batch 'batch', units 16w+4j+hi)
    float c[4], f0[4], f1[4];
    #pragma unroll
    for (int j = 0; j < 4; ++j) {
        const int uj = 16 * w + 4 * j + hi;
        c[j]  = c0[(size_t)batch * HID + uj];
        float hv = h0[(size_t)batch * HID + uj];
        f0[j] = 0.f; f1[j] = 0.f;
        frag[0][w >> 1][(((2 * w + (j >> 1)) & 3) * 16) + col][4 * (j & 1) + hi] =
            (_Float16)hv;
    }

    // ---- prologue: accX = bias + Wih~ . x_0
    const _Float16* xb_base = x16 + (size_t)batch * T_SEQ * DIM + hi * 8;
    f16x8 xf[4];
    #pragma unroll
    for (int ks = 0; ks < 4; ++ks)
        xf[ks] = *reinterpret_cast<const f16x8*>(xb_base + ks * 32);
    f32x4 accX[4];
    #pragma unroll
    for (int j = 0; j < 4; ++j) {
        f32x4 a = bv[j];
        #pragma unroll
        for (int ks = 0; ks < 4; ++ks)
            a = __builtin_amdgcn_mfma_f32_16x16x32_f16(aX[j][ks], xf[ks], a, 0, 0, 0);
        accX[j] = a;
    }

    __syncthreads();   // h frag[0] visible; prologue loads drained

    for (int t = 0; t < T_SEQ; ++t) {
        const int cur = t & 1;
        const int tn  = (t + 1 < T_SEQ) ? t + 1 : t;

        // issue x_{t+1} fragment loads + this step's fc loads (vm, lazy drain)
        #pragma unroll
        for (int ks = 0; ks < 4; ++ks)
            xf[ks] = *reinterpret_cast<const f16x8*>(
                xb_base + (size_t)tn * DIM + ks * 32);
        f32x2 fcu[4];
        #pragma unroll
        for (int j = 0; j < 4; ++j)
            fcu[j] = *reinterpret_cast<const f32x2*>(
                fc2 + 2 * ((size_t)t * HID + 16 * w + 4 * j + hi));

        // h_t B-fragments: 4 conflict-free b128 reads
        f16x8 fh[4];
        #pragma unroll
        for (int ks = 0; ks < 4; ++ks)
            fh[ks] = *reinterpret_cast<const f16x8*>(&frag[cur][ks][l][0]);

        // recurrent GEMM: 4 independent 4-deep chains from precomputed accX
        f32x4 g[4];
        #pragma unroll
        for (int j = 0; j < 4; ++j) {
            f32x4 a = accX[j];
            #pragma unroll
            for (int ks = 0; ks < 4; ++ks)
                a = __builtin_amdgcn_mfma_f32_16x16x32_f16(aH[j][ks], fh[ks], a, 0, 0, 0);
            g[j] = a;
        }

        // next step's accX: independent 4-deep chains (gap filler on MFMA pipe)
        #pragma unroll
        for (int j = 0; j < 4; ++j) {
            f32x4 a = bv[j];
            #pragma unroll
            for (int ks = 0; ks < 4; ++ks)
                a = __builtin_amdgcn_mfma_f32_16x16x32_f16(aX[j][ks], xf[ks], a, 0, 0, 0);
            accX[j] = a;
        }

        // epilogue (trans pipe — overlaps accX MFMAs)
        #pragma unroll
        for (int j = 0; j < 4; ++j) {
            float gi = sig2_(g[j][0]);
            float gf = sig2_(g[j][1]);
            float gg = tanh2_(g[j][2]);
            float go = sig2_(g[j][3]);
            c[j] = fmaf(gf, c[j], gi * gg);
            float hn = go * tanh2_(2.0f * LOG2E * c[j]);
            f0[j] = fmaf(hn, fcu[j].x, f0[j]);
            f1[j] = fmaf(hn, fcu[j].y, f1[j]);
            frag[cur ^ 1][w >> 1][(((2 * w + (j >> 1)) & 3) * 16) + col]
                [4 * (j & 1) + hi] = (_Float16)hn;
        }
        barrier_lgkm();
    }

    // ---- FC head reduction
    float s0 = (f0[0] + f0[1]) + (f0[2] + f0[3]);
    float s1 = (f1[0] + f1[1]) + (f1[2] + f1[3]);
    s0 += __shfl_xor(s0, 16); s0 += __shfl_xor(s0, 32);
    s1 += __shfl_xor(s1, 16); s1 += __shfl_xor(s1, 32);
    if (hi == 0) { red[w][col][0] = s0; red[w][col][1] = s1; }
    __syncthreads();
    if (tid < 32) {
        int b2 = tid >> 1, o = tid & 1;
        float v = 0.f;
        #pragma unroll
        for (int ww = 0; ww < 8; ++ww) v += red[ww][b2][o];
        out[(bg * 16 + b2) * 2 + o] = v + fcb[o];
    }
}

extern "C" void kernel_launch(void* const* d_in, const int* in_sizes, int n_in,
                              void* d_out, int out_size, void* d_ws, size_t ws_size,
                              hipStream_t stream) {
    const float* x    = (const float*)d_in[0];
    const float* h0   = (const float*)d_in[1];
    const float* c0   = (const float*)d_in[2];
    const float* Wih  = (const float*)d_in[3];
    const float* Whh  = (const float*)d_in[4];
    const float* bias = (const float*)d_in[5];
    const float* fcw  = (const float*)d_in[6];
    const float* fcb  = (const float*)d_in[7];
    float* out = (float*)d_out;

    // ws layout: x16 (32 MB) | fc2 (2 MB) | bias_s (2 KB)
    char* wsb = (char*)d_ws;
    _Float16* x16    = (_Float16*)wsb;
    float*    fc2    = (float*)(wsb + (size_t)NBATCH * T_SEQ * DIM * 2);
    float*    bias_s = (float*)(wsb + (size_t)NBATCH * T_SEQ * DIM * 2
                                     + (size_t)T_SEQ * HID * 2 * 4);

    prep<<<512, 256, 0, stream>>>(x, fcw, bias, x16, fc2, bias_s);
    lstm_fused<<<4, 512, 0, stream>>>(x16, Wih, Whh, h0, c0, fc2, fcb, bias_s, out);
}

// Round 11
// 1200.377 us; speedup vs baseline: 2.6448x; 2.6448x over previous
//
#include <hip/hip_runtime.h>

#define T_SEQ 2048
#define NBATCH 64
#define DIM 128      // SEQ_LEN
#define HID 128      // HIDDEN
#define G4 512       // 4*HID
#define GRP 16       // steps per load-batch group (scan)
#define TT 8         // timesteps per block (pre_mfma)

typedef _Float16 h2v   __attribute__((ext_vector_type(2)));
typedef _Float16 f16x8 __attribute__((ext_vector_type(8)));
typedef float    f32x4 __attribute__((ext_vector_type(4)));

__device__ __forceinline__ unsigned pack2(float lo, float hi) {
    h2v v; v.x = (_Float16)lo; v.y = (_Float16)hi;
    return __builtin_bit_cast(unsigned, v);
}
__device__ __forceinline__ float dot2(unsigned a, unsigned b, float c) {
#if __has_builtin(__builtin_amdgcn_fdot2)
    return __builtin_amdgcn_fdot2(__builtin_bit_cast(h2v, a),
                                  __builtin_bit_cast(h2v, b), c, false);
#else
    h2v av = __builtin_bit_cast(h2v, a), bv = __builtin_bit_cast(h2v, b);
    c = fmaf((float)av.x, (float)bv.x, c);
    return fmaf((float)av.y, (float)bv.y, c);
#endif
}
__device__ __forceinline__ float rcp_(float x) { return __builtin_amdgcn_rcpf(x); }
__device__ __forceinline__ float sigmoidf_(float x) {
    return rcp_(1.0f + __expf(-x));
}
__device__ __forceinline__ float tanhf_(float x) {
    return fmaf(2.0f, rcp_(1.0f + __expf(-2.0f * x)), -1.0f);
}
// DPP helpers (quad_perm)
template <int CTRL>
__device__ __forceinline__ float qmov(float v) {
    int r = __builtin_amdgcn_mov_dpp(__builtin_bit_cast(int, v), CTRL, 0xF, 0xF, true);
    return __builtin_bit_cast(float, r);
}
#define QP_XOR1 0xB1   // [1,0,3,2]
#define QP_XOR2 0x4E   // [2,3,0,1]
#define QP_B0   0x00
#define QP_B1   0x55
#define QP_B2   0xAA
#define QP_B3   0xFF

// barrier that drains ONLY lgkm (ds) — vm loads keep flowing across it
__device__ __forceinline__ void barrier_lgkm() {
    asm volatile("s_waitcnt lgkmcnt(0)\n\ts_barrier" ::: "memory");
    __builtin_amdgcn_sched_barrier(0);
}

// ---- prep: x f32 -> f16, same [B][T][DIM] layout ----
__global__ __launch_bounds__(256) void prep(
    const float* __restrict__ x, _Float16* __restrict__ x16)
{
    const size_t gtid   = (size_t)blockIdx.x * blockDim.x + threadIdx.x;
    const size_t stride = (size_t)gridDim.x * blockDim.x;
    const size_t n_x2 = (size_t)NBATCH * T_SEQ * DIM / 2;
    for (size_t i = gtid; i < n_x2; i += stride) {
        float2 v = reinterpret_cast<const float2*>(x)[i];
        h2v p; p.x = (_Float16)v.x; p.y = (_Float16)v.y;
        reinterpret_cast<h2v*>(x16)[i] = p;
    }
}

// ---- Phase 1 (MFMA): pre[lt][b][ch] = f16( x[b][t] . W_ih[:, (ch&3)*128+(ch>>2)] + bias )
// Verified R7 mappings: A-row=lane&15, A-k=(lane>>4)*8+i; B: col=batch, k contiguous;
// C: col=lane&15, row(channel-within-tile)=4*(lane>>4)+reg.
// grid = (tcnt/TT) * 4 blocks, 512 threads (8 waves, wave w -> M-tiles 4w+j).
__global__ __launch_bounds__(512, 2) void pre_mfma(
    const _Float16* __restrict__ x16, // [B][T][DIM]
    const float* __restrict__ Wih,    // [DIM][G4]
    const float* __restrict__ bias,   // [G4] gate-major
    _Float16* __restrict__ pre,       // [tcnt][64][512] channel-interleaved
    int t0)
{
    const int tid = threadIdx.x;
    const int w   = tid >> 6;
    const int l   = tid & 63;
    const int col = l & 15;
    const int hi  = l >> 4;
    const int bg  = blockIdx.x & 3;
    const int lt0 = (blockIdx.x >> 2) * TT;
    const int batch = bg * 16 + col;

    // static A fragments (64 VGPR) + bias accumulator seeds
    f16x8 aX[4][4];
    f32x4 bv[4];
    #pragma unroll
    for (int j = 0; j < 4; ++j) {
        const int chr  = 16 * (4 * w + j) + col;          // A-row channel
        const int wcol = (chr & 3) * HID + (chr >> 2);    // W_ih column
        #pragma unroll
        for (int ks = 0; ks < 4; ++ks) {
            f16x8 a;
            #pragma unroll
            for (int i = 0; i < 8; ++i) {
                int k = ks * 32 + hi * 8 + i;
                a[i] = (_Float16)Wih[(size_t)k * G4 + wcol];
            }
            aX[j][ks] = a;
        }
        #pragma unroll
        for (int r = 0; r < 4; ++r) {
            const int ch = 16 * (4 * w + j) + 4 * hi + r; // C channel
            bv[j][r] = bias[(ch & 3) * HID + (ch >> 2)];
        }
    }

    const _Float16* xb_base = x16 + (size_t)batch * T_SEQ * DIM + hi * 8;

    for (int tt = 0; tt < TT; ++tt) {
        const int lt = lt0 + tt;
        const int t  = t0 + lt;
        f16x8 xf[4];
        #pragma unroll
        for (int ks = 0; ks < 4; ++ks)
            xf[ks] = *reinterpret_cast<const f16x8*>(
                xb_base + (size_t)t * DIM + ks * 32);
        #pragma unroll
        for (int j = 0; j < 4; ++j) {
            f32x4 acc = bv[j];
            #pragma unroll
            for (int ks = 0; ks < 4; ++ks)
                acc = __builtin_amdgcn_mfma_f32_16x16x32_f16(aX[j][ks], xf[ks], acc, 0, 0, 0);
            uint2 o;
            o.x = pack2(acc[0], acc[1]);
            o.y = pack2(acc[2], acc[3]);
            *reinterpret_cast<uint2*>(
                pre + ((size_t)lt * NBATCH + batch) * G4 + 16 * (4 * w + j) + 4 * hi) = o;
        }
    }
}

// ---- Phase 2: scan (R6 structure, 1155 µs measured) + group-ahead load ping-pong.
// grid.x = batch (64 blocks), block = 512: thread = (unit j = tid>>2, quarter q = tid&3).
// state layout (floats): h[64*128] | c[64*128] | facc0[64*128] | facc1[64*128]
__global__ __launch_bounds__(512, 1) void lstm_scan(
    const _Float16* __restrict__ pre, // [tc][B][G4] channel-interleaved
    const float* __restrict__ Whh,    // [HID][G4]
    const float* __restrict__ h0,
    const float* __restrict__ c0,
    const float* __restrict__ fcw,    // [2][T*HID]
    const float* __restrict__ fcb,
    float* __restrict__ state,
    float* __restrict__ out,          // [B][2]
    int t0, int tc)
{
    __shared__ __align__(16) _Float16 h_sh[2][HID];
    __shared__ float red[2][HID];

    const int tid = threadIdx.x;
    const int j = tid >> 2;           // unit
    const int q = tid & 3;            // k-quarter / gate owner
    const int b = blockIdx.x;
    const bool q1 = (q & 1) != 0;
    const bool q2 = (q & 2) != 0;
    const bool isg = (q == 2);

    float* st_h  = state;
    float* st_c  = state + NBATCH * HID;
    float* st_f0 = state + 2 * NBATCH * HID;
    float* st_f1 = state + 3 * NBATCH * HID;

    // W_hh fragments: gate g, k in [32q, 32q+32), packed pairs (64 VGPRs)
    unsigned wpk[4][16];
    #pragma unroll
    for (int g = 0; g < 4; ++g)
        #pragma unroll
        for (int i = 0; i < 16; ++i) {
            int k0 = q * 32 + 2 * i;
            wpk[g][i] = pack2(Whh[(size_t)k0 * G4 + g * HID + j],
                              Whh[(size_t)(k0 + 1) * G4 + g * HID + j]);
        }

    float c, facc = 0.f, hj;
    if (t0 == 0) {
        hj = h0[b * HID + j]; c = c0[b * HID + j];
    } else {
        hj = st_h[b * HID + j];
        c  = st_c[b * HID + j];
        if (q == 2) facc = st_f0[b * HID + j];
        if (q == 3) facc = st_f1[b * HID + j];
    }
    if (q == 0) h_sh[0][j] = (_Float16)hj;

    const float* fp = fcw + ((q == 3) ? (size_t)T_SEQ * HID : 0) + j;  // q>=2 only
    const size_t pstep = (size_t)NBATCH * G4;
    const _Float16* pb = pre + (size_t)b * G4 + tid;

    // prologue: load group 0 into A arrays
    unsigned short prA[GRP], prB[GRP];
    float fwA[GRP], fwB[GRP];
    #pragma unroll
    for (int s = 0; s < GRP; ++s)
        prA[s] = __builtin_bit_cast(unsigned short, pb[(size_t)s * pstep]);
    if (q >= 2) {
        #pragma unroll
        for (int s = 0; s < GRP; ++s)
            fwA[s] = fp[(size_t)(t0 + s) * HID];
    }

    __syncthreads();

#define LOADG(PR, FW, TGN)                                                   \
    {                                                                        \
        const int tgl = (TGN);                                               \
        _Pragma("unroll")                                                    \
        for (int s = 0; s < GRP; ++s)                                        \
            PR[s] = __builtin_bit_cast(unsigned short,                       \
                        pb[(size_t)(tgl + s) * pstep]);                      \
        if (q >= 2) {                                                        \
            _Pragma("unroll")                                                \
            for (int s = 0; s < GRP; ++s)                                    \
                FW[s] = fp[(size_t)(t0 + tgl + s) * HID];                    \
        }                                                                    \
    }

#define STEP16(PR, FW)                                                       \
    _Pragma("unroll")                                                        \
    for (int s = 0; s < GRP; ++s) {                                          \
        const int cur = s & 1;                                               \
        const uint4* hp = reinterpret_cast<const uint4*>(&h_sh[cur][q * 32]);\
        float pv = (float)__builtin_bit_cast(_Float16, PR[s]);               \
        float a0 = (q == 0) ? pv : 0.f;                                      \
        float a1 = (q == 1) ? pv : 0.f;                                      \
        float a2 = (q == 2) ? pv : 0.f;                                      \
        float a3 = (q == 3) ? pv : 0.f;                                      \
        _Pragma("unroll")                                                    \
        for (int m = 0; m < 4; ++m) {                                        \
            uint4 hv = hp[m];                                                \
            a0 = dot2(hv.x, wpk[0][4 * m + 0], a0);                          \
            a1 = dot2(hv.x, wpk[1][4 * m + 0], a1);                          \
            a2 = dot2(hv.x, wpk[2][4 * m + 0], a2);                          \
            a3 = dot2(hv.x, wpk[3][4 * m + 0], a3);                          \
            a0 = dot2(hv.y, wpk[0][4 * m + 1], a0);                          \
            a1 = dot2(hv.y, wpk[1][4 * m + 1], a1);                          \
            a2 = dot2(hv.y, wpk[2][4 * m + 1], a2);                          \
            a3 = dot2(hv.y, wpk[3][4 * m + 1], a3);                          \
            a0 = dot2(hv.z, wpk[0][4 * m + 2], a0);                          \
            a1 = dot2(hv.z, wpk[1][4 * m + 2], a1);                          \
            a2 = dot2(hv.z, wpk[2][4 * m + 2], a2);                          \
            a3 = dot2(hv.z, wpk[3][4 * m + 2], a3);                          \
            a0 = dot2(hv.w, wpk[0][4 * m + 3], a0);                          \
            a1 = dot2(hv.w, wpk[1][4 * m + 3], a1);                          \
            a2 = dot2(hv.w, wpk[2][4 * m + 3], a2);                          \
            a3 = dot2(hv.w, wpk[3][4 * m + 3], a3);                          \
        }                                                                    \
        float t01  = q1 ? a1 : a0;                                           \
        float t01o = q1 ? a0 : a1;                                           \
        t01 += qmov<QP_XOR1>(t01o);                                          \
        float t23  = q1 ? a3 : a2;                                           \
        float t23o = q1 ? a2 : a3;                                           \
        t23 += qmov<QP_XOR1>(t23o);                                          \
        float tq  = q2 ? t23 : t01;                                          \
        float tqo = q2 ? t01 : t23;                                          \
        tq += qmov<QP_XOR2>(tqo);                                            \
        float e   = __expf(isg ? -2.0f * tq : -tq);                          \
        float v   = rcp_(1.0f + e);                                          \
        float act = isg ? fmaf(2.0f, v, -1.0f) : v;                          \
        float gi = qmov<QP_B0>(act);                                         \
        float gf = qmov<QP_B1>(act);                                         \
        float gg = qmov<QP_B2>(act);                                         \
        float go = qmov<QP_B3>(act);                                         \
        c = fmaf(gf, c, gi * gg);                                            \
        float hn = go * tanhf_(c);                                           \
        hj = hn;                                                             \
        if (q == 0) h_sh[cur ^ 1][j] = (_Float16)hn;                         \
        if (q >= 2) facc = fmaf(hn, FW[s], facc);                            \
        barrier_lgkm();                                                      \
    }

    for (int tg = 0; tg < tc; tg += 2 * GRP) {
        LOADG(prB, fwB, tg + GRP);                       // next group (in range)
        STEP16(prA, fwA);
        const int tga = (tg + 2 * GRP < tc) ? tg + 2 * GRP : tg;  // clamp
        LOADG(prA, fwA, tga);
        STEP16(prB, fwB);
    }
#undef LOADG
#undef STEP16

    if (t0 + tc >= T_SEQ) {
        if (q == 2) red[0][j] = facc;
        if (q == 3) red[1][j] = facc;
        __syncthreads();
        if (tid < 128) {
            int o = tid >> 6;
            int l = tid & 63;
            float v = red[o][l] + red[o][l + 64];
            v += __shfl_xor(v, 32); v += __shfl_xor(v, 16);
            v += __shfl_xor(v, 8);  v += __shfl_xor(v, 4);
            v += __shfl_xor(v, 2);  v += __shfl_xor(v, 1);
            if (l == 0) out[b * 2 + o] = v + fcb[o];
        }
    } else {
        if (q == 0) { st_h[b * HID + j] = hj; st_c[b * HID + j] = c; }
        if (q == 2) st_f0[b * HID + j] = facc;
        if (q == 3) st_f1[b * HID + j] = facc;
    }
}

extern "C" void kernel_launch(void* const* d_in, const int* in_sizes, int n_in,
                              void* d_out, int out_size, void* d_ws, size_t ws_size,
                              hipStream_t stream) {
    const float* x    = (const float*)d_in[0];
    const float* h0   = (const float*)d_in[1];
    const float* c0   = (const float*)d_in[2];
    const float* Wih  = (const float*)d_in[3];
    const float* Whh  = (const float*)d_in[4];
    const float* bias = (const float*)d_in[5];
    const float* fcw  = (const float*)d_in[6];
    const float* fcb  = (const float*)d_in[7];
    float* out = (float*)d_out;

    // ws layout: x16 (32 MB) | state (128 KB) | pre chunk (f16, 64 KB/step)
    char* wsb = (char*)d_ws;
    _Float16* x16 = (_Float16*)wsb;
    float* state  = (float*)(wsb + (size_t)NBATCH * T_SEQ * DIM * 2);
    const size_t state_floats = (size_t)4 * NBATCH * HID;
    _Float16* pre = (_Float16*)(state + state_floats);

    const size_t head = (size_t)NBATCH * T_SEQ * DIM * 2 + state_floats * 4;
    const size_t per_t_bytes = (size_t)NBATCH * G4 * sizeof(_Float16);
    size_t avail = (ws_size > head) ? ws_size - head : 0;
    int Tc = (int)(avail / per_t_bytes);
    Tc &= ~(2 * GRP - 1);           // multiple of 32 (ping-pong groups, TT divides)
    if (Tc < 2 * GRP) Tc = 2 * GRP; // fallback (ws known >= 268 MB from R1)
    if (Tc > T_SEQ) Tc = T_SEQ;

    prep<<<512, 256, 0, stream>>>(x, x16);
    for (int t0 = 0; t0 < T_SEQ; t0 += Tc) {
        int tc = (t0 + Tc <= T_SEQ) ? Tc : (T_SEQ - t0);   // multiple of 32
        pre_mfma<<<(tc / TT) * 4, 512, 0, stream>>>(x16, Wih, bias, pre, t0);
        lstm_scan<<<64, 512, 0, stream>>>(pre, Whh, h0, c0, fcw, fcb,
                                          state, out, t0, tc);
    }
}

// Round 12
// 1162.345 us; speedup vs baseline: 2.7313x; 1.0327x over previous
//
#include <hip/hip_runtime.h>

#define T_SEQ 2048
#define NBATCH 64
#define DIM 128      // SEQ_LEN
#define HID 128      // HIDDEN
#define G4 512       // 4*HID
#define GRP 16       // steps per load-batch group (scan)
#define TT 8         // timesteps per block (pre_mfma)
#define LOG2E 1.44269504088896f

typedef _Float16 h2v   __attribute__((ext_vector_type(2)));
typedef _Float16 f16x8 __attribute__((ext_vector_type(8)));
typedef float    f32x4 __attribute__((ext_vector_type(4)));

__device__ __forceinline__ unsigned pack2(float lo, float hi) {
    h2v v; v.x = (_Float16)lo; v.y = (_Float16)hi;
    return __builtin_bit_cast(unsigned, v);
}
__device__ __forceinline__ float dot2(unsigned a, unsigned b, float c) {
#if __has_builtin(__builtin_amdgcn_fdot2)
    return __builtin_amdgcn_fdot2(__builtin_bit_cast(h2v, a),
                                  __builtin_bit_cast(h2v, b), c, false);
#else
    h2v av = __builtin_bit_cast(h2v, a), bv = __builtin_bit_cast(h2v, b);
    c = fmaf((float)av.x, (float)bv.x, c);
    return fmaf((float)av.y, (float)bv.y, c);
#endif
}
__device__ __forceinline__ float rcp_(float x)  { return __builtin_amdgcn_rcpf(x); }
__device__ __forceinline__ float exp2_(float x) { return __builtin_amdgcn_exp2f(x); }
// DPP helpers (quad_perm)
template <int CTRL>
__device__ __forceinline__ float qmov(float v) {
    int r = __builtin_amdgcn_mov_dpp(__builtin_bit_cast(int, v), CTRL, 0xF, 0xF, true);
    return __builtin_bit_cast(float, r);
}
#define QP_XOR1 0xB1   // [1,0,3,2]
#define QP_XOR2 0x4E   // [2,3,0,1]
#define QP_B0   0x00
#define QP_B1   0x55
#define QP_B2   0xAA
#define QP_B3   0xFF

// barrier that drains ONLY lgkm (ds) — vm loads keep flowing across it
__device__ __forceinline__ void barrier_lgkm() {
    asm volatile("s_waitcnt lgkmcnt(0)\n\ts_barrier" ::: "memory");
    __builtin_amdgcn_sched_barrier(0);
}

// ---- prep: x f32 -> f16, same [B][T][DIM] layout ----
__global__ __launch_bounds__(256) void prep(
    const float* __restrict__ x, _Float16* __restrict__ x16)
{
    const size_t gtid   = (size_t)blockIdx.x * blockDim.x + threadIdx.x;
    const size_t stride = (size_t)gridDim.x * blockDim.x;
    const size_t n_x2 = (size_t)NBATCH * T_SEQ * DIM / 2;
    for (size_t i = gtid; i < n_x2; i += stride) {
        float2 v = reinterpret_cast<const float2*>(x)[i];
        h2v p; p.x = (_Float16)v.x; p.y = (_Float16)v.y;
        reinterpret_cast<h2v*>(x16)[i] = p;
    }
}

// ---- Phase 1 (MFMA): pre[lt][b][ch] = f16( -sc_g * (x[b][t].W_ih[:,col(ch)] + bias) )
// where sc_g = log2e (2*log2e for gate g). Channel ch = 4*unit+gate.
// Verified mappings (R7): A-row=lane&15, A-k=(lane>>4)*8+i; C: col=lane&15,
// row=4*(lane>>4)+reg. grid = (tcnt/TT)*4 blocks, 512 threads.
__global__ __launch_bounds__(512, 2) void pre_mfma(
    const _Float16* __restrict__ x16, // [B][T][DIM]
    const float* __restrict__ Wih,    // [DIM][G4]
    const float* __restrict__ bias,   // [G4] gate-major
    _Float16* __restrict__ pre,       // [tcnt][64][512] channel-interleaved, scaled
    int t0)
{
    const int tid = threadIdx.x;
    const int w   = tid >> 6;
    const int l   = tid & 63;
    const int col = l & 15;
    const int hi  = l >> 4;
    const int bg  = blockIdx.x & 3;
    const int lt0 = (blockIdx.x >> 2) * TT;
    const int batch = bg * 16 + col;

    // static A fragments (64 VGPR), scaled by -log2e / -2log2e, + scaled bias
    f16x8 aX[4][4];
    f32x4 bv[4];
    #pragma unroll
    for (int j = 0; j < 4; ++j) {
        const int chr  = 16 * (4 * w + j) + col;          // A-row channel
        const int wcol = (chr & 3) * HID + (chr >> 2);    // W_ih column
        const float sc = ((chr & 3) == 2) ? -2.0f * LOG2E : -LOG2E;
        #pragma unroll
        for (int ks = 0; ks < 4; ++ks) {
            f16x8 a;
            #pragma unroll
            for (int i = 0; i < 8; ++i) {
                int k = ks * 32 + hi * 8 + i;
                a[i] = (_Float16)(Wih[(size_t)k * G4 + wcol] * sc);
            }
            aX[j][ks] = a;
        }
        #pragma unroll
        for (int r = 0; r < 4; ++r) {
            const int ch = 16 * (4 * w + j) + 4 * hi + r; // C channel
            const float scr = ((ch & 3) == 2) ? -2.0f * LOG2E : -LOG2E;
            bv[j][r] = bias[(ch & 3) * HID + (ch >> 2)] * scr;
        }
    }

    const _Float16* xb_base = x16 + (size_t)batch * T_SEQ * DIM + hi * 8;

    for (int tt = 0; tt < TT; ++tt) {
        const int lt = lt0 + tt;
        const int t  = t0 + lt;
        f16x8 xf[4];
        #pragma unroll
        for (int ks = 0; ks < 4; ++ks)
            xf[ks] = *reinterpret_cast<const f16x8*>(
                xb_base + (size_t)t * DIM + ks * 32);
        #pragma unroll
        for (int j = 0; j < 4; ++j) {
            f32x4 acc = bv[j];
            #pragma unroll
            for (int ks = 0; ks < 4; ++ks)
                acc = __builtin_amdgcn_mfma_f32_16x16x32_f16(aX[j][ks], xf[ks], acc, 0, 0, 0);
            uint2 o;
            o.x = pack2(acc[0], acc[1]);
            o.y = pack2(acc[2], acc[3]);
            *reinterpret_cast<uint2*>(
                pre + ((size_t)lt * NBATCH + batch) * G4 + 16 * (4 * w + j) + 4 * hi) = o;
        }
    }
}

// ---- Phase 2: scan. grid.x = batch (64), block = 512: thread = (unit j=tid>>2, q=tid&3).
// All weights/pre pre-scaled by -log2e (-2log2e for gate g): every lane's activation
// is v = rcp(1+exp2(a)); tanh folded as 2v-1 into fma forms. h trace -> global (f16);
// FC head is a separate kernel. state layout (floats): h[64*128] | c[64*128]
__global__ __launch_bounds__(512, 1) void lstm_scan(
    const _Float16* __restrict__ pre, // [tc][B][G4] channel-interleaved, scaled
    const float* __restrict__ Whh,    // [HID][G4]
    const float* __restrict__ h0,
    const float* __restrict__ c0,
    float* __restrict__ state,
    _Float16* __restrict__ trace,     // [B][T][HID]
    int t0, int tc)
{
    __shared__ __align__(16) _Float16 h_sh[2][HID];

    const int tid = threadIdx.x;
    const int j = tid >> 2;           // unit
    const int q = tid & 3;            // k-quarter / gate owner
    const int b = blockIdx.x;
    const bool q1 = (q & 1) != 0;
    const bool q2 = (q & 2) != 0;

    float* st_h = state;
    float* st_c = state + NBATCH * HID;

    // W_hh fragments: gate g, k in [32q,32q+32), packed pairs, scaled (64 VGPRs)
    unsigned wpk[4][16];
    #pragma unroll
    for (int g = 0; g < 4; ++g) {
        const float sc = (g == 2) ? -2.0f * LOG2E : -LOG2E;
        #pragma unroll
        for (int i = 0; i < 16; ++i) {
            int k0 = q * 32 + 2 * i;
            wpk[g][i] = pack2(Whh[(size_t)k0 * G4 + g * HID + j] * sc,
                              Whh[(size_t)(k0 + 1) * G4 + g * HID + j] * sc);
        }
    }

    float c, hj;
    if (t0 == 0) {
        hj = h0[b * HID + j]; c = c0[b * HID + j];
    } else {
        hj = st_h[b * HID + j];
        c  = st_c[b * HID + j];
    }
    if (q == 0) h_sh[0][j] = (_Float16)hj;

    const size_t pstep = (size_t)NBATCH * G4;
    const _Float16* pb = pre + (size_t)b * G4 + tid;
    _Float16* tb = trace + ((size_t)b * T_SEQ + t0) * HID + j;

    // prologue: load group 0
    unsigned short prA[GRP], prB[GRP];
    #pragma unroll
    for (int s = 0; s < GRP; ++s)
        prA[s] = __builtin_bit_cast(unsigned short, pb[(size_t)s * pstep]);

    __syncthreads();

#define LOADG(PR, TGN)                                                       \
    {                                                                        \
        const int tgl = (TGN);                                               \
        _Pragma("unroll")                                                    \
        for (int s = 0; s < GRP; ++s)                                        \
            PR[s] = __builtin_bit_cast(unsigned short,                       \
                        pb[(size_t)(tgl + s) * pstep]);                      \
    }

#define STEP16(PR, TG)                                                       \
    _Pragma("unroll")                                                        \
    for (int s = 0; s < GRP; ++s) {                                          \
        const int cur = s & 1;                                               \
        const uint4* hp = reinterpret_cast<const uint4*>(&h_sh[cur][q * 32]);\
        float a0 = 0.f, a1 = 0.f, a2 = 0.f, a3 = 0.f;                        \
        _Pragma("unroll")                                                    \
        for (int m = 0; m < 4; ++m) {                                        \
            uint4 hv = hp[m];                                                \
            a0 = dot2(hv.x, wpk[0][4 * m + 0], a0);                          \
            a1 = dot2(hv.x, wpk[1][4 * m + 0], a1);                          \
            a2 = dot2(hv.x, wpk[2][4 * m + 0], a2);                          \
            a3 = dot2(hv.x, wpk[3][4 * m + 0], a3);                          \
            a0 = dot2(hv.y, wpk[0][4 * m + 1], a0);                          \
            a1 = dot2(hv.y, wpk[1][4 * m + 1], a1);                          \
            a2 = dot2(hv.y, wpk[2][4 * m + 1], a2);                          \
            a3 = dot2(hv.y, wpk[3][4 * m + 1], a3);                          \
            a0 = dot2(hv.z, wpk[0][4 * m + 2], a0);                          \
            a1 = dot2(hv.z, wpk[1][4 * m + 2], a1);                          \
            a2 = dot2(hv.z, wpk[2][4 * m + 2], a2);                          \
            a3 = dot2(hv.z, wpk[3][4 * m + 2], a3);                          \
            a0 = dot2(hv.w, wpk[0][4 * m + 3], a0);                          \
            a1 = dot2(hv.w, wpk[1][4 * m + 3], a1);                          \
            a2 = dot2(hv.w, wpk[2][4 * m + 3], a2);                          \
            a3 = dot2(hv.w, wpk[3][4 * m + 3], a3);                          \
        }                                                                    \
        float t01  = q1 ? a1 : a0;                                           \
        float t01o = q1 ? a0 : a1;                                           \
        t01 += qmov<QP_XOR1>(t01o);                                          \
        float t23  = q1 ? a3 : a2;                                           \
        float t23o = q1 ? a2 : a3;                                           \
        t23 += qmov<QP_XOR1>(t23o);                                          \
        float tq  = q2 ? t23 : t01;                                          \
        float tqo = q2 ? t01 : t23;                                          \
        tq += qmov<QP_XOR2>(tqo);                                            \
        tq += (float)__builtin_bit_cast(_Float16, PR[s]);                    \
        float v = rcp_(1.0f + exp2_(tq));                                    \
        float gi = qmov<QP_B0>(v);                                           \
        float gf = qmov<QP_B1>(v);                                           \
        float vg = qmov<QP_B2>(v);                                           \
        float go = qmov<QP_B3>(v);                                           \
        c = fmaf(gf, c, fmaf(gi + gi, vg, -gi));                             \
        float vc = rcp_(1.0f + exp2_(-2.0f * LOG2E * c));                    \
        float hn = fmaf(go + go, vc, -go);                                   \
        hj = hn;                                                             \
        _Float16 h16 = (_Float16)hn;                                         \
        if (q == 0) {                                                        \
            h_sh[cur ^ 1][j] = h16;                                          \
            tb[(size_t)((TG) + s) * HID] = h16;                              \
        }                                                                    \
        barrier_lgkm();                                                      \
    }

    for (int tg = 0; tg < tc; tg += 2 * GRP) {
        LOADG(prB, tg + GRP);                            // next group (in range)
        STEP16(prA, tg);
        const int tga = (tg + 2 * GRP < tc) ? tg + 2 * GRP : tg;  // clamp
        LOADG(prA, tga);
        STEP16(prB, tg + GRP);
    }
#undef LOADG
#undef STEP16

    if (t0 + tc < T_SEQ) {
        if (q == 0) { st_h[b * HID + j] = hj; st_c[b * HID + j] = c; }
    }
}

// ---- Phase 3: FC head. out[b][o] = fcb[o] + sum_t,j trace[b][t][j]*fcw[o][t*HID+j]
__global__ __launch_bounds__(256) void fc_head(
    const _Float16* __restrict__ trace,  // [B][T][HID]
    const float* __restrict__ fcw,       // [2][T*HID]
    const float* __restrict__ fcb,
    float* __restrict__ out)             // [B][2]
{
    __shared__ float red[4][2];
    const int b = blockIdx.x, tid = threadIdx.x;
    const _Float16* tbase = trace + (size_t)b * (T_SEQ * HID);
    const float* w0 = fcw;
    const float* w1 = fcw + (size_t)T_SEQ * HID;

    float s0 = 0.f, s1 = 0.f;
    for (int i = tid * 8; i < T_SEQ * HID; i += 256 * 8) {
        uint4 tv = *reinterpret_cast<const uint4*>(tbase + i);
        float wa0[8], wa1[8];
        *reinterpret_cast<float4*>(&wa0[0]) = *reinterpret_cast<const float4*>(w0 + i);
        *reinterpret_cast<float4*>(&wa0[4]) = *reinterpret_cast<const float4*>(w0 + i + 4);
        *reinterpret_cast<float4*>(&wa1[0]) = *reinterpret_cast<const float4*>(w1 + i);
        *reinterpret_cast<float4*>(&wa1[4]) = *reinterpret_cast<const float4*>(w1 + i + 4);
        const unsigned* tw = reinterpret_cast<const unsigned*>(&tv);
        #pragma unroll
        for (int e = 0; e < 4; ++e) {
            h2v hh = __builtin_bit_cast(h2v, tw[e]);
            float hx = (float)hh.x, hy = (float)hh.y;
            s0 = fmaf(hx, wa0[2 * e], s0);
            s0 = fmaf(hy, wa0[2 * e + 1], s0);
            s1 = fmaf(hx, wa1[2 * e], s1);
            s1 = fmaf(hy, wa1[2 * e + 1], s1);
        }
    }
    #pragma unroll
    for (int d = 32; d >= 1; d >>= 1) {
        s0 += __shfl_xor(s0, d);
        s1 += __shfl_xor(s1, d);
    }
    const int w = tid >> 6;
    if ((tid & 63) == 0) { red[w][0] = s0; red[w][1] = s1; }
    __syncthreads();
    if (tid < 2) {
        float v = red[0][tid] + red[1][tid] + red[2][tid] + red[3][tid];
        out[b * 2 + tid] = v + fcb[tid];
    }
}

extern "C" void kernel_launch(void* const* d_in, const int* in_sizes, int n_in,
                              void* d_out, int out_size, void* d_ws, size_t ws_size,
                              hipStream_t stream) {
    const float* x    = (const float*)d_in[0];
    const float* h0   = (const float*)d_in[1];
    const float* c0   = (const float*)d_in[2];
    const float* Wih  = (const float*)d_in[3];
    const float* Whh  = (const float*)d_in[4];
    const float* bias = (const float*)d_in[5];
    const float* fcw  = (const float*)d_in[6];
    const float* fcb  = (const float*)d_in[7];
    float* out = (float*)d_out;

    // ws layout: x16 (32 MB) | trace (32 MB) | state (64 KB) | pre chunk (64 KB/step)
    char* wsb = (char*)d_ws;
    _Float16* x16   = (_Float16*)wsb;
    _Float16* trace = (_Float16*)(wsb + (size_t)NBATCH * T_SEQ * DIM * 2);
    float* state    = (float*)(wsb + 2 * (size_t)NBATCH * T_SEQ * DIM * 2);
    const size_t state_floats = (size_t)2 * NBATCH * HID;
    _Float16* pre = (_Float16*)(state + state_floats);

    const size_t head = 2 * (size_t)NBATCH * T_SEQ * DIM * 2 + state_floats * 4;
    const size_t per_t_bytes = (size_t)NBATCH * G4 * sizeof(_Float16);
    size_t avail = (ws_size > head) ? ws_size - head : 0;
    int Tc = (int)(avail / per_t_bytes);
    Tc &= ~(2 * GRP - 1);           // multiple of 32 (ping-pong groups; TT divides)
    if (Tc < 2 * GRP) Tc = 2 * GRP; // fallback (ws known >= 268 MB from R1)
    if (Tc > T_SEQ) Tc = T_SEQ;

    prep<<<512, 256, 0, stream>>>(x, x16);
    for (int t0 = 0; t0 < T_SEQ; t0 += Tc) {
        int tc = (t0 + Tc <= T_SEQ) ? Tc : (T_SEQ - t0);   // multiple of 32
        pre_mfma<<<(tc / TT) * 4, 512, 0, stream>>>(x16, Wih, bias, pre, t0);
        lstm_scan<<<64, 512, 0, stream>>>(pre, Whh, h0, c0, state, trace, t0, tc);
    }
    fc_head<<<64, 256, 0, stream>>>(trace, fcw, fcb, out);
}